// Round 4
// baseline (103.323 us; speedup 1.0000x reference)
//
#include <hip/hip_runtime.h>
#include <hip/hip_bf16.h>

// DenseEnergyLoss on MI355X. N=4, K=21, H=W=128 -> OH=OW=64, P=4096.
// loss = 0.1*(-0.5)/(N*P) * sum_{n,p,q} exp(-0.5*max(|f_p-f_q|^2,0)) * gate_p * <seg_p, seg_q>
// Symmetrized: gate_p -> (gate_p+gate_q)/2; upper-triangular 128x128 tiles only
// (diag weight 0.5, off-diag 1.0 after folding the x2).
// R4: q-records are wave-uniform -> read them via the SCALAR path (s_load from
// global, SGPR operands) instead of LDS. R3 was LDS-delivery-bound: 5x
// ds_read_b128 = 60 LDS-pipe cyc/q-iter vs only 24 CU-cyc of VALU demand.
// No LDS staging at all now; q-strip base made uniform with readfirstlane.

constexpr int N_ = 4, K_ = 21, H_ = 128, W_ = 128, P_ = 4096;
constexpr int T_ = 128;                  // tile size (p and q)
constexpr int NT = P_ / T_;              // 32 tiles per dim
constexpr int NTRI = NT * (NT + 1) / 2;  // 528 upper-tri tile pairs per n
constexpr int REC = 20;                  // 32-bit words per point record (80 B)
constexpr float INV_RGB = 1.0f / 15.0f;
constexpr float INV_XY = 1.0f / 40.0f;   // 1/(SIGMA_XY*SCALE)
constexpr float LOG2E = 1.4426950408889634f;
constexpr float NEG_HALF_LOG2E = -0.72134752044448170f;
constexpr float OUT_SCALE = -0.05f / 16384.0f; // 0.1 * -0.5 / (N*P)

typedef _Float16 half2_t __attribute__((ext_vector_type(2)));

#if __has_builtin(__builtin_amdgcn_fdot2)
#define FDOT2(a, b, c) __builtin_amdgcn_fdot2((a), (b), (c), false)
#else
static __device__ __forceinline__ float FDOT2(half2_t a, half2_t b, float c) {
  return c + (float)a.x * (float)b.x + (float)a.y * (float)b.y;
}
#endif

// Record layout (20 floats): [0..10] seg_m as half2 pairs (k=2j,2j+1; last hi=0),
// [11..15] f0..f4 (f32), [16] cs = -0.5*log2e*|f|^2, [17] gate, [18..19] pad.

__global__ void __launch_bounds__(256) prep_kernel(
    const float* __restrict__ img, const float* __restrict__ seg,
    const float* __restrict__ roi, const float* __restrict__ lab,
    float* __restrict__ rec, float* __restrict__ out) {
  int idx = blockIdx.x * 256 + threadIdx.x; // n*P + p
  if (blockIdx.x == 0 && threadIdx.x == 0) out[0] = 0.0f; // energy runs after prep
  int n = idx >> 12;
  int p = idx & (P_ - 1);
  int y = p >> 6, x = p & 63;
  int iy = 2 * y, ix = 2 * x;
  const size_t hw = (size_t)H_ * W_;

  float r = roi[(size_t)n * hw + iy * W_ + ix];
  float lb = lab[(size_t)n * hw + iy * W_ + ix];
  bool unlabeled = ((int)lb == 255);

  const float* sb = seg + (size_t)n * K_ * hw + (size_t)iy * W_ + ix;
  float sm[22];
  float mx = -1e30f;
#pragma unroll
  for (int k = 0; k < K_; k++) {
    const float* s = sb + (size_t)k * hw;
    float v = 0.25f * (s[0] + s[1] + s[W_] + s[W_ + 1]); // bilinear @0.5 == 2x2 avg
    mx = fmaxf(mx, v);
    sm[k] = v * r; // seg_m = seg_s * roi
  }
  sm[21] = 0.0f;

  float o[REC];
#pragma unroll
  for (int j = 0; j < 11; j++) {
    half2_t h;
    h.x = (_Float16)sm[2 * j];
    h.y = (_Float16)sm[2 * j + 1];
    o[j] = __builtin_bit_cast(float, h);
  }
  float f0 = (float)x * INV_XY;
  float f1 = (float)y * INV_XY;
  const float* ib = img + (size_t)n * 3 * hw + (size_t)iy * W_ + ix;
  float f2 = ib[0] * INV_RGB;
  float f3 = ib[hw] * INV_RGB;
  float f4 = ib[2 * hw] * INV_RGB;
  o[11] = f0; o[12] = f1; o[13] = f2; o[14] = f3; o[15] = f4;
  float sq = f0 * f0;
  sq = fmaf(f1, f1, sq); sq = fmaf(f2, f2, sq);
  sq = fmaf(f3, f3, sq); sq = fmaf(f4, f4, sq);
  o[16] = NEG_HALF_LOG2E * sq;
  float g = unlabeled ? 1.0f : (r - mx);
  o[17] = fmaxf(g, 0.0f);
  o[18] = 0.0f; o[19] = 0.0f;

  float4* dst = (float4*)(rec + (size_t)idx * REC);
  const float4* srcv = (const float4*)o;
#pragma unroll
  for (int j = 0; j < REC / 4; j++) dst[j] = srcv[j];
}

__global__ void __launch_bounds__(256) energy_kernel(
    const float* __restrict__ rec, float* __restrict__ out) {
  // Decode upper-triangular tile pair (pb <= qb) from blockIdx.x in [0, 528).
  int t = blockIdx.x;
  int pb = 0;
  while (t >= NT - pb) { t -= NT - pb; pb++; }
  int qb = pb + t;
  int n = blockIdx.y;
  int tid = threadIdx.x;
  int lane = tid & 63;
  // Force wave index to be compiler-provably uniform so the q-loop addresses
  // are uniform -> scalar loads (s_load) instead of LDS/VMEM broadcast.
  int wave = __builtin_amdgcn_readfirstlane(tid >> 6);

  const float* base = rec + (size_t)n * P_ * REC;

  // Each wave covers all 128 p's (MP=2 per lane) x its own 32-q strip.
  half2_t sp[2][11];
  float fp[2][5], csp[2], gp[2];
#pragma unroll
  for (int i = 0; i < 2; i++) {
    const float4* rp4 = (const float4*)(base + (size_t)(pb * T_ + lane + i * 64) * REC);
    float4 b0 = rp4[0], b1 = rp4[1], b2 = rp4[2], b3 = rp4[3], b4 = rp4[4];
    sp[i][0] = __builtin_bit_cast(half2_t, b0.x);
    sp[i][1] = __builtin_bit_cast(half2_t, b0.y);
    sp[i][2] = __builtin_bit_cast(half2_t, b0.z);
    sp[i][3] = __builtin_bit_cast(half2_t, b0.w);
    sp[i][4] = __builtin_bit_cast(half2_t, b1.x);
    sp[i][5] = __builtin_bit_cast(half2_t, b1.y);
    sp[i][6] = __builtin_bit_cast(half2_t, b1.z);
    sp[i][7] = __builtin_bit_cast(half2_t, b1.w);
    sp[i][8] = __builtin_bit_cast(half2_t, b2.x);
    sp[i][9] = __builtin_bit_cast(half2_t, b2.y);
    sp[i][10] = __builtin_bit_cast(half2_t, b2.z);
    fp[i][0] = b2.w;
    fp[i][1] = b3.x; fp[i][2] = b3.y; fp[i][3] = b3.z; fp[i][4] = b3.w;
    csp[i] = b4.x; gp[i] = b4.y;
  }

  // q-records: wave-uniform scalar reads straight from global (no LDS).
  const float4* qbase = (const float4*)(base + (size_t)(qb * T_ + wave * 32) * REC);

  float acc = 0.0f;
#pragma unroll 2
  for (int qj = 0; qj < 32; qj++) {
    float4 a0 = qbase[qj * 5 + 0];
    float4 a1 = qbase[qj * 5 + 1];
    float4 a2 = qbase[qj * 5 + 2];
    float4 a3 = qbase[qj * 5 + 3];
    float4 a4 = qbase[qj * 5 + 4];
    half2_t q0 = __builtin_bit_cast(half2_t, a0.x);
    half2_t q1 = __builtin_bit_cast(half2_t, a0.y);
    half2_t q2 = __builtin_bit_cast(half2_t, a0.z);
    half2_t q3 = __builtin_bit_cast(half2_t, a0.w);
    half2_t q4 = __builtin_bit_cast(half2_t, a1.x);
    half2_t q5 = __builtin_bit_cast(half2_t, a1.y);
    half2_t q6 = __builtin_bit_cast(half2_t, a1.z);
    half2_t q7 = __builtin_bit_cast(half2_t, a1.w);
    half2_t q8 = __builtin_bit_cast(half2_t, a2.x);
    half2_t q9 = __builtin_bit_cast(half2_t, a2.y);
    half2_t q10 = __builtin_bit_cast(half2_t, a2.z);
    float f0q = a2.w, f1q = a3.x, f2q = a3.y, f3q = a3.z, f4q = a3.w;
    float csq = a4.x, gq = a4.y;
#pragma unroll
    for (int i = 0; i < 2; i++) {
      // K-contraction: 11 half2 dot2s, two accumulators for ILP.
      float Ga = FDOT2(sp[i][0], q0, 0.0f);
      float Gb = FDOT2(sp[i][1], q1, 0.0f);
      Ga = FDOT2(sp[i][2], q2, Ga);
      Gb = FDOT2(sp[i][3], q3, Gb);
      Ga = FDOT2(sp[i][4], q4, Ga);
      Gb = FDOT2(sp[i][5], q5, Gb);
      Ga = FDOT2(sp[i][6], q6, Ga);
      Gb = FDOT2(sp[i][7], q7, Gb);
      Ga = FDOT2(sp[i][8], q8, Ga);
      Gb = FDOT2(sp[i][9], q9, Gb);
      Ga = FDOT2(sp[i][10], q10, Ga);
      // 5-dim feature dot (fp32).
      float dot = fp[i][0] * f0q;
      dot = fmaf(fp[i][1], f1q, dot);
      dot = fmaf(fp[i][2], f2q, dot);
      dot = fmaf(fp[i][3], f3q, dot);
      dot = fmaf(fp[i][4], f4q, dot);
      // A = exp(-0.5*max(d2,0)) = min(exp2(cs_p+cs_q+log2e*dot), 1)
      float arg = fmaf(LOG2E, dot, csp[i] + csq);
      float A = __builtin_amdgcn_exp2f(arg);
      A = fminf(A, 1.0f);
      acc = fmaf(A * (Ga + Gb), gp[i] + gq, acc);
    }
  }

  // Reduce: wave shuffle, then cross-wave via LDS, one atomic per block.
#pragma unroll
  for (int off = 32; off > 0; off >>= 1) acc += __shfl_down(acc, off, 64);
  __shared__ float wsum[4];
  if (lane == 0) wsum[wave] = acc;
  __syncthreads();
  if (tid == 0) {
    float s = (wsum[0] + wsum[1]) + (wsum[2] + wsum[3]);
    float wb = (pb == qb) ? 0.5f : 1.0f; // symmetrized-gate 1/2 folded with off-diag x2
    atomicAdd(out, s * wb * OUT_SCALE);
  }
}

extern "C" void kernel_launch(void* const* d_in, const int* in_sizes, int n_in,
                              void* d_out, int out_size, void* d_ws, size_t ws_size,
                              hipStream_t stream) {
  const float* images = (const float*)d_in[0];
  const float* segs = (const float*)d_in[1];
  const float* rois = (const float*)d_in[2];
  const float* labels = (const float*)d_in[3];
  float* out = (float*)d_out;
  float* rec = (float*)d_ws; // N*P*REC*4 = 1.31 MB

  prep_kernel<<<dim3(N_ * P_ / 256), dim3(256), 0, stream>>>(images, segs, rois, labels, rec, out);
  energy_kernel<<<dim3(NTRI, N_), dim3(256), 0, stream>>>(rec, out);
}

// Round 5
// 99.760 us; speedup vs baseline: 1.0357x; 1.0357x over previous
//
#include <hip/hip_runtime.h>
#include <hip/hip_bf16.h>

// DenseEnergyLoss on MI355X. N=4, K=21, H=W=128 -> OH=OW=64, P=4096.
// loss = 0.1*(-0.5)/(N*P) * sum_{n,p,q} exp(-0.5*max(|f_p-f_q|^2,0)) * gate_p * <seg_p, seg_q>
// Symmetrized: gate_p -> (gate_p+gate_q)/2; upper-triangular 128x128 tiles only
// (diag weight 0.5, off-diag 1.0 after folding the x2).
// R5: kill the same-address atomicAdd tail (2112 serialized device-scope RMWs
// ~= 25-30 us). Blocks store partials to distinct addresses; a 1-block reduce
// kernel sums them. Energy inner loop identical to R4.

constexpr int N_ = 4, K_ = 21, H_ = 128, W_ = 128, P_ = 4096;
constexpr int T_ = 128;                  // tile size (p and q)
constexpr int NT = P_ / T_;              // 32 tiles per dim
constexpr int NTRI = NT * (NT + 1) / 2;  // 528 upper-tri tile pairs per n
constexpr int NBLK = NTRI * N_;          // 2112 energy blocks
constexpr int REC = 20;                  // 32-bit words per point record (80 B)
constexpr float INV_RGB = 1.0f / 15.0f;
constexpr float INV_XY = 1.0f / 40.0f;   // 1/(SIGMA_XY*SCALE)
constexpr float LOG2E = 1.4426950408889634f;
constexpr float NEG_HALF_LOG2E = -0.72134752044448170f;
constexpr float OUT_SCALE = -0.05f / 16384.0f; // 0.1 * -0.5 / (N*P)

typedef _Float16 half2_t __attribute__((ext_vector_type(2)));

#if __has_builtin(__builtin_amdgcn_fdot2)
#define FDOT2(a, b, c) __builtin_amdgcn_fdot2((a), (b), (c), false)
#else
static __device__ __forceinline__ float FDOT2(half2_t a, half2_t b, float c) {
  return c + (float)a.x * (float)b.x + (float)a.y * (float)b.y;
}
#endif

// Record layout (20 floats): [0..10] seg_m as half2 pairs (k=2j,2j+1; last hi=0),
// [11..15] f0..f4 (f32), [16] cs = -0.5*log2e*|f|^2, [17] gate, [18..19] pad.

__global__ void __launch_bounds__(256) prep_kernel(
    const float* __restrict__ img, const float* __restrict__ seg,
    const float* __restrict__ roi, const float* __restrict__ lab,
    float* __restrict__ rec) {
  int idx = blockIdx.x * 256 + threadIdx.x; // n*P + p
  int n = idx >> 12;
  int p = idx & (P_ - 1);
  int y = p >> 6, x = p & 63;
  int iy = 2 * y, ix = 2 * x;
  const size_t hw = (size_t)H_ * W_;

  float r = roi[(size_t)n * hw + iy * W_ + ix];
  float lb = lab[(size_t)n * hw + iy * W_ + ix];
  bool unlabeled = ((int)lb == 255);

  const float* sb = seg + (size_t)n * K_ * hw + (size_t)iy * W_ + ix;
  float sm[22];
  float mx = -1e30f;
#pragma unroll
  for (int k = 0; k < K_; k++) {
    const float* s = sb + (size_t)k * hw;
    float v = 0.25f * (s[0] + s[1] + s[W_] + s[W_ + 1]); // bilinear @0.5 == 2x2 avg
    mx = fmaxf(mx, v);
    sm[k] = v * r; // seg_m = seg_s * roi
  }
  sm[21] = 0.0f;

  float o[REC];
#pragma unroll
  for (int j = 0; j < 11; j++) {
    half2_t h;
    h.x = (_Float16)sm[2 * j];
    h.y = (_Float16)sm[2 * j + 1];
    o[j] = __builtin_bit_cast(float, h);
  }
  float f0 = (float)x * INV_XY;
  float f1 = (float)y * INV_XY;
  const float* ib = img + (size_t)n * 3 * hw + (size_t)iy * W_ + ix;
  float f2 = ib[0] * INV_RGB;
  float f3 = ib[hw] * INV_RGB;
  float f4 = ib[2 * hw] * INV_RGB;
  o[11] = f0; o[12] = f1; o[13] = f2; o[14] = f3; o[15] = f4;
  float sq = f0 * f0;
  sq = fmaf(f1, f1, sq); sq = fmaf(f2, f2, sq);
  sq = fmaf(f3, f3, sq); sq = fmaf(f4, f4, sq);
  o[16] = NEG_HALF_LOG2E * sq;
  float g = unlabeled ? 1.0f : (r - mx);
  o[17] = fmaxf(g, 0.0f);
  o[18] = 0.0f; o[19] = 0.0f;

  float4* dst = (float4*)(rec + (size_t)idx * REC);
  const float4* srcv = (const float4*)o;
#pragma unroll
  for (int j = 0; j < REC / 4; j++) dst[j] = srcv[j];
}

__global__ void __launch_bounds__(256) energy_kernel(
    const float* __restrict__ rec, float* __restrict__ partial) {
  // Decode upper-triangular tile pair (pb <= qb) from blockIdx.x in [0, 528).
  int t = blockIdx.x;
  int pb = 0;
  while (t >= NT - pb) { t -= NT - pb; pb++; }
  int qb = pb + t;
  int n = blockIdx.y;
  int tid = threadIdx.x;
  int lane = tid & 63;
  int wave = __builtin_amdgcn_readfirstlane(tid >> 6);

  const float* base = rec + (size_t)n * P_ * REC;

  // Each wave covers all 128 p's (MP=2 per lane) x its own 32-q strip.
  half2_t sp[2][11];
  float fp[2][5], csp[2], gp[2];
#pragma unroll
  for (int i = 0; i < 2; i++) {
    const float4* rp4 = (const float4*)(base + (size_t)(pb * T_ + lane + i * 64) * REC);
    float4 b0 = rp4[0], b1 = rp4[1], b2 = rp4[2], b3 = rp4[3], b4 = rp4[4];
    sp[i][0] = __builtin_bit_cast(half2_t, b0.x);
    sp[i][1] = __builtin_bit_cast(half2_t, b0.y);
    sp[i][2] = __builtin_bit_cast(half2_t, b0.z);
    sp[i][3] = __builtin_bit_cast(half2_t, b0.w);
    sp[i][4] = __builtin_bit_cast(half2_t, b1.x);
    sp[i][5] = __builtin_bit_cast(half2_t, b1.y);
    sp[i][6] = __builtin_bit_cast(half2_t, b1.z);
    sp[i][7] = __builtin_bit_cast(half2_t, b1.w);
    sp[i][8] = __builtin_bit_cast(half2_t, b2.x);
    sp[i][9] = __builtin_bit_cast(half2_t, b2.y);
    sp[i][10] = __builtin_bit_cast(half2_t, b2.z);
    fp[i][0] = b2.w;
    fp[i][1] = b3.x; fp[i][2] = b3.y; fp[i][3] = b3.z; fp[i][4] = b3.w;
    csp[i] = b4.x; gp[i] = b4.y;
  }

  // q-records: wave-uniform reads straight from global (no LDS).
  const float4* qbase = (const float4*)(base + (size_t)(qb * T_ + wave * 32) * REC);

  float acc = 0.0f;
#pragma unroll 2
  for (int qj = 0; qj < 32; qj++) {
    float4 a0 = qbase[qj * 5 + 0];
    float4 a1 = qbase[qj * 5 + 1];
    float4 a2 = qbase[qj * 5 + 2];
    float4 a3 = qbase[qj * 5 + 3];
    float4 a4 = qbase[qj * 5 + 4];
    half2_t q0 = __builtin_bit_cast(half2_t, a0.x);
    half2_t q1 = __builtin_bit_cast(half2_t, a0.y);
    half2_t q2 = __builtin_bit_cast(half2_t, a0.z);
    half2_t q3 = __builtin_bit_cast(half2_t, a0.w);
    half2_t q4 = __builtin_bit_cast(half2_t, a1.x);
    half2_t q5 = __builtin_bit_cast(half2_t, a1.y);
    half2_t q6 = __builtin_bit_cast(half2_t, a1.z);
    half2_t q7 = __builtin_bit_cast(half2_t, a1.w);
    half2_t q8 = __builtin_bit_cast(half2_t, a2.x);
    half2_t q9 = __builtin_bit_cast(half2_t, a2.y);
    half2_t q10 = __builtin_bit_cast(half2_t, a2.z);
    float f0q = a2.w, f1q = a3.x, f2q = a3.y, f3q = a3.z, f4q = a3.w;
    float csq = a4.x, gq = a4.y;
#pragma unroll
    for (int i = 0; i < 2; i++) {
      float Ga = FDOT2(sp[i][0], q0, 0.0f);
      float Gb = FDOT2(sp[i][1], q1, 0.0f);
      Ga = FDOT2(sp[i][2], q2, Ga);
      Gb = FDOT2(sp[i][3], q3, Gb);
      Ga = FDOT2(sp[i][4], q4, Ga);
      Gb = FDOT2(sp[i][5], q5, Gb);
      Ga = FDOT2(sp[i][6], q6, Ga);
      Gb = FDOT2(sp[i][7], q7, Gb);
      Ga = FDOT2(sp[i][8], q8, Ga);
      Gb = FDOT2(sp[i][9], q9, Gb);
      Ga = FDOT2(sp[i][10], q10, Ga);
      float dot = fp[i][0] * f0q;
      dot = fmaf(fp[i][1], f1q, dot);
      dot = fmaf(fp[i][2], f2q, dot);
      dot = fmaf(fp[i][3], f3q, dot);
      dot = fmaf(fp[i][4], f4q, dot);
      float arg = fmaf(LOG2E, dot, csp[i] + csq);
      float A = __builtin_amdgcn_exp2f(arg);
      A = fminf(A, 1.0f);
      acc = fmaf(A * (Ga + Gb), gp[i] + gq, acc);
    }
  }

  // Reduce within block; store partial to a distinct address (no atomics).
#pragma unroll
  for (int off = 32; off > 0; off >>= 1) acc += __shfl_down(acc, off, 64);
  __shared__ float wsum[4];
  if (lane == 0) wsum[wave] = acc;
  __syncthreads();
  if (tid == 0) {
    float s = (wsum[0] + wsum[1]) + (wsum[2] + wsum[3]);
    float wb = (pb == qb) ? 0.5f : 1.0f; // symmetrized-gate 1/2 folded with off-diag x2
    partial[blockIdx.y * NTRI + blockIdx.x] = s * wb;
  }
}

__global__ void __launch_bounds__(256) reduce_kernel(
    const float* __restrict__ partial, float* __restrict__ out) {
  int tid = threadIdx.x;
  float acc = 0.0f;
  for (int i = tid; i < NBLK; i += 256) acc += partial[i];
#pragma unroll
  for (int off = 32; off > 0; off >>= 1) acc += __shfl_down(acc, off, 64);
  __shared__ float wsum[4];
  int lane = tid & 63, wave = tid >> 6;
  if (lane == 0) wsum[wave] = acc;
  __syncthreads();
  if (tid == 0) {
    float s = (wsum[0] + wsum[1]) + (wsum[2] + wsum[3]);
    out[0] = s * OUT_SCALE;
  }
}

extern "C" void kernel_launch(void* const* d_in, const int* in_sizes, int n_in,
                              void* d_out, int out_size, void* d_ws, size_t ws_size,
                              hipStream_t stream) {
  const float* images = (const float*)d_in[0];
  const float* segs = (const float*)d_in[1];
  const float* rois = (const float*)d_in[2];
  const float* labels = (const float*)d_in[3];
  float* out = (float*)d_out;
  float* rec = (float*)d_ws;                        // N*P*REC*4 = 1.31 MB
  float* partial = (float*)d_ws + (size_t)N_ * P_ * REC; // +2112 floats

  prep_kernel<<<dim3(N_ * P_ / 256), dim3(256), 0, stream>>>(images, segs, rois, labels, rec);
  energy_kernel<<<dim3(NTRI, N_), dim3(256), 0, stream>>>(rec, partial);
  reduce_kernel<<<dim3(1), dim3(256), 0, stream>>>(partial, out);
}

// Round 6
// 84.231 us; speedup vs baseline: 1.2267x; 1.1844x over previous
//
#include <hip/hip_runtime.h>
#include <hip/hip_bf16.h>

// DenseEnergyLoss on MI355X. N=4, K=21, H=W=128 -> OH=OW=64, P=4096.
// loss = 0.1*(-0.5)/(N*P) * sum_{n,p,q} exp(-0.5*max(|f_p-f_q|^2,0)) * gate_p * <seg_p, seg_q>
// Symmetrized: gate_p -> (gate_p+gate_q)/2; upper-triangular 128x128 tile-pairs,
// diag tiles weighted 0.5 (off-diag x2 folded).
// R6: both inner dot products (K=21 seg contraction, 5-dim feature dot) moved to
// v_mfma_f32_16x16x32_f16. R2-R5 were VALU-issue-bound (~2x hand count: dot2
// lowered to cvt+fma). Epilogue per element: arg-fma, exp2, min, mul, fma.
// Fragment layouts per verified m89/m120 mappings:
//   A/B: point = lane&15, k = (lane>>4)*8 + j (j=0..7)
//   C/D: col = lane&15, row = (lane>>4)*4 + reg

constexpr int N_ = 4, K_ = 21, H_ = 128, W_ = 128, P_ = 4096;
constexpr int T_ = 128;                  // tile size (p and q)
constexpr int NT = P_ / T_;              // 32 tiles per dim
constexpr int NTRI = NT * (NT + 1) / 2;  // 528 upper-tri tile pairs per n
constexpr int NBLK = NTRI * N_;          // 2112 energy blocks
constexpr float INV_RGB = 1.0f / 15.0f;
constexpr float INV_XY = 1.0f / 40.0f;   // 1/(SIGMA_XY*SCALE)
constexpr float LOG2E = 1.4426950408889634f;
constexpr float NEG_HALF_LOG2E = -0.72134752044448170f;
constexpr float OUT_SCALE = -0.05f / 16384.0f; // 0.1 * -0.5 / (N*P)

typedef _Float16 half8 __attribute__((ext_vector_type(8)));
typedef float floatx4 __attribute__((ext_vector_type(4)));

// Workspace layout (all within d_ws):
//   segh : N*P*32 f16  (seg_m zero-padded to 32 ch)   = 1 MB
//   feath: N*P*8  f16  (5 features + 3 zeros)          = 256 KB
//   scal : N*P float2  {cs, gate}                      = 128 KB
//   partial: NBLK floats

__global__ void __launch_bounds__(256) prep_kernel(
    const float* __restrict__ img, const float* __restrict__ seg,
    const float* __restrict__ roi, const float* __restrict__ lab,
    _Float16* __restrict__ segh, _Float16* __restrict__ feath,
    float2* __restrict__ scal) {
  int idx = blockIdx.x * 256 + threadIdx.x; // n*P + p
  int n = idx >> 12;
  int p = idx & (P_ - 1);
  int y = p >> 6, x = p & 63;
  int iy = 2 * y, ix = 2 * x;
  const size_t hw = (size_t)H_ * W_;

  float r = roi[(size_t)n * hw + iy * W_ + ix];
  float lb = lab[(size_t)n * hw + iy * W_ + ix];
  bool unlabeled = ((int)lb == 255);

  const float* sb = seg + (size_t)n * K_ * hw + (size_t)iy * W_ + ix;
  _Float16 sh[32];
  float mx = -1e30f;
#pragma unroll
  for (int k = 0; k < K_; k++) {
    const float* s = sb + (size_t)k * hw;
    float v = 0.25f * (s[0] + s[1] + s[W_] + s[W_ + 1]); // bilinear @0.5 == 2x2 avg
    mx = fmaxf(mx, v);
    sh[k] = (_Float16)(v * r); // seg_m = seg_s * roi, rounded to f16
  }
#pragma unroll
  for (int k = K_; k < 32; k++) sh[k] = (_Float16)0.0f;

  // Features, rounded to f16; cs computed from the ROUNDED values so the
  // diagonal d2 cancels exactly (A=1).
  const float* ib = img + (size_t)n * 3 * hw + (size_t)iy * W_ + ix;
  _Float16 fh[8];
  fh[0] = (_Float16)((float)x * INV_XY);
  fh[1] = (_Float16)((float)y * INV_XY);
  fh[2] = (_Float16)(ib[0] * INV_RGB);
  fh[3] = (_Float16)(ib[hw] * INV_RGB);
  fh[4] = (_Float16)(ib[2 * hw] * INV_RGB);
  fh[5] = (_Float16)0.0f; fh[6] = (_Float16)0.0f; fh[7] = (_Float16)0.0f;
  float sq = 0.0f;
#pragma unroll
  for (int j = 0; j < 5; j++) { float v = (float)fh[j]; sq = fmaf(v, v, sq); }

  // Vector stores.
  float4* sdst = (float4*)(segh + (size_t)idx * 32);
  const float4* ssrc = (const float4*)sh;
#pragma unroll
  for (int j = 0; j < 4; j++) sdst[j] = ssrc[j];
  *(float4*)(feath + (size_t)idx * 8) = *(const float4*)fh;

  float g = unlabeled ? 1.0f : (r - mx);
  scal[idx] = make_float2(NEG_HALF_LOG2E * sq, fmaxf(g, 0.0f));
}

__global__ void __launch_bounds__(256) energy_kernel(
    const _Float16* __restrict__ segh, const _Float16* __restrict__ feath,
    const float2* __restrict__ scal, float* __restrict__ partial) {
  // Decode upper-triangular tile pair (pb <= qb) from blockIdx.x in [0, 528).
  int t = blockIdx.x;
  int pb = 0;
  while (t >= NT - pb) { t -= NT - pb; pb++; }
  int qb = pb + t;
  int n = blockIdx.y;
  int tid = threadIdx.x;
  int lane = tid & 63, wave = tid >> 6;
  int m = lane & 15, quad = lane >> 4;

  const _Float16* segn = segh + (size_t)n * P_ * 32;
  const _Float16* featn = feath + (size_t)n * P_ * 8;
  const float2* scaln = scal + (size_t)n * P_;

  // Stage per-point {cs, gate} for the p-tile and q-tile into LDS.
  __shared__ float2 sp_[T_], sq_[T_];
  for (int i = tid; i < T_; i += 256) {
    sp_[i] = scaln[pb * T_ + i];
    sq_[i] = scaln[qb * T_ + i];
  }
  __syncthreads();

  // Each wave: 2 p-strips (rows 32*wave .. 32*wave+31) x all 8 q-strips.
  half8 aseg[2], afeat[2];
  const half8 zfrag = {};
#pragma unroll
  for (int s = 0; s < 2; s++) {
    int prow = pb * T_ + (2 * wave + s) * 16 + m;
    aseg[s] = *(const half8*)(segn + (size_t)prow * 32 + quad * 8);
    half8 f = *(const half8*)(featn + (size_t)prow * 8);
    afeat[s] = (quad == 0) ? f : zfrag;
  }
  // Per-lane p-side scalars for the 4 accumulator rows of each strip.
  float cspv[2][4], gpv[2][4];
#pragma unroll
  for (int s = 0; s < 2; s++)
#pragma unroll
    for (int r = 0; r < 4; r++) {
      float2 tpr = sp_[(2 * wave + s) * 16 + quad * 4 + r];
      cspv[s][r] = tpr.x; gpv[s][r] = tpr.y;
    }

  float acc = 0.0f;
#pragma unroll 2
  for (int qs = 0; qs < 8; qs++) {
    int qrow = qb * T_ + qs * 16 + m;
    half8 bseg = *(const half8*)(segn + (size_t)qrow * 32 + quad * 8);
    half8 bf = *(const half8*)(featn + (size_t)qrow * 8);
    half8 bfeat = (quad == 0) ? bf : zfrag;
    float2 qsc = sq_[qs * 16 + m]; // {csq, gq} for this lane's column
#pragma unroll
    for (int s = 0; s < 2; s++) {
      floatx4 G = {0.0f, 0.0f, 0.0f, 0.0f};
      floatx4 D = {0.0f, 0.0f, 0.0f, 0.0f};
      G = __builtin_amdgcn_mfma_f32_16x16x32_f16(aseg[s], bseg, G, 0, 0, 0);
      D = __builtin_amdgcn_mfma_f32_16x16x32_f16(afeat[s], bfeat, D, 0, 0, 0);
#pragma unroll
      for (int r = 0; r < 4; r++) {
        float arg = fmaf(LOG2E, D[r], cspv[s][r] + qsc.x);
        float A = __builtin_amdgcn_exp2f(arg);
        A = fminf(A, 1.0f);
        acc = fmaf(A * G[r], gpv[s][r] + qsc.y, acc);
      }
    }
  }

  // Reduce within block; store partial to a distinct address (no atomics).
#pragma unroll
  for (int off = 32; off > 0; off >>= 1) acc += __shfl_down(acc, off, 64);
  __shared__ float wsum[4];
  if (lane == 0) wsum[wave] = acc;
  __syncthreads();
  if (tid == 0) {
    float s = (wsum[0] + wsum[1]) + (wsum[2] + wsum[3]);
    float wb = (pb == qb) ? 0.5f : 1.0f;
    partial[blockIdx.y * NTRI + blockIdx.x] = s * wb;
  }
}

__global__ void __launch_bounds__(256) reduce_kernel(
    const float* __restrict__ partial, float* __restrict__ out) {
  int tid = threadIdx.x;
  float acc = 0.0f;
  for (int i = tid; i < NBLK; i += 256) acc += partial[i];
#pragma unroll
  for (int off = 32; off > 0; off >>= 1) acc += __shfl_down(acc, off, 64);
  __shared__ float wsum[4];
  int lane = tid & 63, wave = tid >> 6;
  if (lane == 0) wsum[wave] = acc;
  __syncthreads();
  if (tid == 0) {
    float s = (wsum[0] + wsum[1]) + (wsum[2] + wsum[3]);
    out[0] = s * OUT_SCALE;
  }
}

extern "C" void kernel_launch(void* const* d_in, const int* in_sizes, int n_in,
                              void* d_out, int out_size, void* d_ws, size_t ws_size,
                              hipStream_t stream) {
  const float* images = (const float*)d_in[0];
  const float* segs = (const float*)d_in[1];
  const float* rois = (const float*)d_in[2];
  const float* labels = (const float*)d_in[3];
  float* out = (float*)d_out;

  char* ws = (char*)d_ws;
  _Float16* segh = (_Float16*)ws;                        // N*P*32*2 = 1 MB
  _Float16* feath = (_Float16*)(ws + (size_t)N_ * P_ * 32 * 2);
  float2* scal = (float2*)(ws + (size_t)N_ * P_ * 32 * 2 + (size_t)N_ * P_ * 8 * 2);
  float* partial = (float*)(ws + (size_t)N_ * P_ * 32 * 2 + (size_t)N_ * P_ * 8 * 2 +
                            (size_t)N_ * P_ * sizeof(float2));

  prep_kernel<<<dim3(N_ * P_ / 256), dim3(256), 0, stream>>>(
      images, segs, rois, labels, segh, feath, scal);
  energy_kernel<<<dim3(NTRI, N_), dim3(256), 0, stream>>>(segh, feath, scal, partial);
  reduce_kernel<<<dim3(1), dim3(256), 0, stream>>>(partial, out);
}